// Round 4
// baseline (38.213 us; speedup 1.0000x reference)
//
#include <hip/hip_runtime.h>

// HungarianMatcher batched cost matrix.
// B=64, Q=900, T=300, C=80. out[b][q][t] f32.
// cost = 5*cbbox + (2*ccls + 2) - 2*inter/uni - 2*uni/ca
//
// R4 = R3 structure (targets in registers, serial q-loop, 2 broadcasts +
// 1 gather per element) with occupancy restored: QTILE 75->25 gives a
// 2304-block grid (~9 blocks/CU submitted, 32-wave/CU cap reachable)
// vs R3's 768-block / 15-wave ceiling that left VALUBusy at 50%.

constexpr int B = 64, Q = 900, T = 300, C = 80;
constexpr int QTILE = 25;            // 900 % 25 == 0 -> 36 q-tiles, grid 2304
constexpr int BLOCK = 320;           // 5 waves; threads 300..319 idle in main
constexpr float ALPHA = 0.25f;
constexpr float EPSF  = 1e-8f;

__device__ __forceinline__ float fast_rcp(float x) {
    return __builtin_amdgcn_rcpf(x);   // v_rcp_f32, ~1 ulp
}

__global__ __launch_bounds__(BLOCK) void matcher_cost_kernel(
    const float* __restrict__ logits,   // [B,Q,C]
    const float* __restrict__ pboxes,   // [B,Q,4] cxcywh
    const int*   __restrict__ tlabels,  // [B,T]
    const float* __restrict__ tboxes,   // [B,T,4] cxcywh
    float* __restrict__ out)            // [B,Q,T]
{
    __shared__ float  s_cls[QTILE * C]; // 2*ccls + 2  (8000 B)
    __shared__ float4 s_pA[QTILE];      // cx,cy,w,h
    __shared__ float4 s_pB[QTILE];      // x0,y0,x1,y1   (area = w*h, derived)

    const int bid = blockIdx.x;
    const int b   = bid / (Q / QTILE);
    const int q0  = (bid % (Q / QTILE)) * QTILE;
    const int tid = threadIdx.x;

    // ---- target box for this thread's t, kept in registers ----
    float tcx = 0.f, tcy = 0.f, tw = 0.f, th = 0.f;
    float tx0 = 0.f, ty0 = 0.f, tx1 = 0.f, ty1 = 0.f, ta = 0.f;
    int lab = 0;
    if (tid < T) {
        float4 bx = *(const float4*)(tboxes + ((size_t)b * T + tid) * 4);
        tcx = bx.x; tcy = bx.y; tw = bx.z; th = bx.w;
        tx0 = bx.x - 0.5f * bx.z; ty0 = bx.y - 0.5f * bx.w;
        tx1 = bx.x + 0.5f * bx.z; ty1 = bx.y + 0.5f * bx.w;
        ta  = bx.z * bx.w;
        lab = tlabels[(size_t)b * T + tid];
    }

    // ---- pred boxes for this q-tile -> LDS (read later as broadcasts) ----
    if (tid < QTILE) {
        float4 bx = *(const float4*)(pboxes + ((size_t)b * Q + q0 + tid) * 4);
        float x0 = bx.x - 0.5f * bx.z, y0 = bx.y - 0.5f * bx.w;
        float x1 = bx.x + 0.5f * bx.z, y1 = bx.y + 0.5f * bx.w;
        s_pA[tid] = bx;
        s_pB[tid] = make_float4(x0, y0, x1, y1);
    }

    // ---- focal class table (pre-scaled: 2*ccls + 2), each (q,c) once ----
    {
        const float* lg = logits + ((size_t)b * Q + q0) * C;  // 2000 contiguous
        for (int i = tid; i < QTILE * C; i += BLOCK) {
            float x  = lg[i];
            float pr = fast_rcp(1.0f + __expf(-x));
            float om = 1.0f - pr;
            float pos = ALPHA * om * om * (-__logf(pr + EPSF));
            float neg = (1.0f - ALPHA) * pr * pr * (-__logf(om + EPSF));
            s_cls[i] = 2.0f * (pos - neg) + 2.0f;
        }
    }

    __syncthreads();

    if (tid >= T) return;

    const float* clscol = s_cls + lab;      // per-lane base; ql*C*4 as imm offset
    float* op = out + ((size_t)b * Q + q0) * T + tid;
    #pragma unroll 5
    for (int ql = 0; ql < QTILE; ++ql) {
        float4 pA = s_pA[ql];               // broadcast b128
        float4 pB = s_pB[ql];               // broadcast b128
        float  pa = pA.z * pA.w;            // pred area = w*h
        float clsv = clscol[ql * C];        // random 4B gather, imm offset

        float cbbox = fabsf(pA.x - tcx) + fabsf(pA.y - tcy) +
                      fabsf(pA.z - tw ) + fabsf(pA.w - th );

        float iw = fmaxf(fminf(pB.z, tx1) - fmaxf(pB.x, tx0), 0.0f);
        float ih = fmaxf(fminf(pB.w, ty1) - fmaxf(pB.y, ty0), 0.0f);
        float inter = iw * ih;
        float uni   = pa + ta - inter;

        float cw = fmaxf(pB.z, tx1) - fminf(pB.x, tx0);  // >= 0 always
        float ch = fmaxf(pB.w, ty1) - fminf(pB.y, ty0);  // >= 0 always
        float ca = cw * ch;

        // cost = 5*cbbox + (2*ccls + 2) - 2*inter/uni - 2*uni/ca
        float c = fmaf(5.0f, cbbox, clsv);
        c = fmaf(-2.0f * inter, fast_rcp(uni), c);
        c = fmaf(-2.0f * uni,   fast_rcp(ca),  c);

        if (c != c) c = 1.0f;   // nan_to_num; |finite c| << 1e6 so clamp is no-op

        op[(size_t)ql * T] = c; // lane-contiguous 4B store, coalesced
    }
}

extern "C" void kernel_launch(void* const* d_in, const int* in_sizes, int n_in,
                              void* d_out, int out_size, void* d_ws, size_t ws_size,
                              hipStream_t stream) {
    const float* logits  = (const float*)d_in[0];  // [B,Q,C]
    const float* pboxes  = (const float*)d_in[1];  // [B,Q,4]
    const int*   tlabels = (const int*)  d_in[2];  // [B,T]
    const float* tboxes  = (const float*)d_in[3];  // [B,T,4]
    float* out = (float*)d_out;                    // [B,Q,T]

    dim3 grid(B * (Q / QTILE));   // 2304 blocks
    dim3 block(BLOCK);
    matcher_cost_kernel<<<grid, block, 0, stream>>>(logits, pboxes, tlabels, tboxes, out);
}

// Round 5
// 37.278 us; speedup vs baseline: 1.0251x; 1.0251x over previous
//
#include <hip/hip_runtime.h>

// HungarianMatcher batched cost matrix.
// B=64, Q=900, T=300, C=80. out[b][q][t] f32.
// cost = 5*cbbox + (2*ccls + 2) - 2*inter/uni - 2*uni/ca
//
// R5: kill per-iteration LDS latency. Targets live in registers (R3);
// class costs are PRE-GATHERED into registers before the q-loop; pred
// boxes are read at wave-uniform addresses (compiler -> s_load, scalar
// pipe). Main loop = pure VALU + 1 coalesced store, no ds_read, no
// lgkmcnt stall per iteration. R3/R4 burned ~450 cyc/iter waiting on
// a 3-ds_read -> waitcnt -> compute chain with ~2 blocks/CU resident.

constexpr int B = 64, Q = 900, T = 300, C = 80;
constexpr int QTILE = 20;            // 900 % 20 == 0 -> 45 q-tiles, grid 2880
constexpr int BLOCK = 320;           // 5 waves; threads 300..319 idle in main
constexpr float ALPHA = 0.25f;
constexpr float EPSF  = 1e-8f;

__device__ __forceinline__ float fast_rcp(float x) {
    return __builtin_amdgcn_rcpf(x);   // v_rcp_f32, ~1 ulp
}

__global__ __launch_bounds__(BLOCK) void matcher_cost_kernel(
    const float* __restrict__ logits,   // [B,Q,C]
    const float* __restrict__ pboxes,   // [B,Q,4] cxcywh
    const int*   __restrict__ tlabels,  // [B,T]
    const float* __restrict__ tboxes,   // [B,T,4] cxcywh
    float* __restrict__ out)            // [B,Q,T]
{
    __shared__ float s_cls[QTILE * C];  // 2*ccls + 2  (6400 B) -- only LDS use

    const int bid = blockIdx.x;
    const int b   = bid / (Q / QTILE);
    const int q0  = (bid % (Q / QTILE)) * QTILE;
    const int tid = threadIdx.x;

    // ---- target box for this thread's t, kept in registers ----
    float tcx = 0.f, tcy = 0.f, tw = 0.f, th = 0.f;
    float tx0 = 0.f, ty0 = 0.f, tx1 = 0.f, ty1 = 0.f, ta = 0.f;
    int lab = 0;
    if (tid < T) {
        float4 bx = *(const float4*)(tboxes + ((size_t)b * T + tid) * 4);
        tcx = bx.x; tcy = bx.y; tw = bx.z; th = bx.w;
        tx0 = bx.x - 0.5f * bx.z; ty0 = bx.y - 0.5f * bx.w;
        tx1 = bx.x + 0.5f * bx.z; ty1 = bx.y + 0.5f * bx.w;
        ta  = bx.z * bx.w;
        lab = tlabels[(size_t)b * T + tid];
    }

    // ---- focal class table (pre-scaled: 2*ccls + 2), each (q,c) once ----
    {
        const float* lg = logits + ((size_t)b * Q + q0) * C;  // 1600 contiguous
        #pragma unroll
        for (int s = 0; s < QTILE * C / BLOCK; ++s) {         // exactly 5
            int i = s * BLOCK + tid;
            float x  = lg[i];
            float pr = fast_rcp(1.0f + __expf(-x));
            float om = 1.0f - pr;
            float pos = ALPHA * om * om * (-__logf(pr + EPSF));
            float neg = (1.0f - ALPHA) * pr * pr * (-__logf(om + EPSF));
            s_cls[i] = 2.0f * (pos - neg) + 2.0f;
        }
    }

    __syncthreads();

    if (tid >= T) return;

    // ---- pre-gather this thread's QTILE class values into registers ----
    float clsr[QTILE];
    {
        const float* cp = s_cls + lab;      // per-lane base; ql*C*4 imm offsets
        #pragma unroll
        for (int ql = 0; ql < QTILE; ++ql)
            clsr[ql] = cp[ql * C];          // pipelined ds_read_b32, one wait
    }

    // ---- main loop: pure VALU + uniform scalar loads + coalesced store ----
    const float4* pb = (const float4*)(pboxes + ((size_t)b * Q + q0) * 4);
    float* op = out + ((size_t)b * Q + q0) * T + tid;

    #pragma unroll
    for (int ql = 0; ql < QTILE; ++ql) {
        float4 pA = pb[ql];                 // wave-uniform -> s_load_dwordx4
        float px0 = pA.x - 0.5f * pA.z, py0 = pA.y - 0.5f * pA.w;
        float px1 = pA.x + 0.5f * pA.z, py1 = pA.y + 0.5f * pA.w;
        float pa  = pA.z * pA.w;

        float cbbox = fabsf(pA.x - tcx) + fabsf(pA.y - tcy) +
                      fabsf(pA.z - tw ) + fabsf(pA.w - th );

        float iw = fmaxf(fminf(px1, tx1) - fmaxf(px0, tx0), 0.0f);
        float ih = fmaxf(fminf(py1, ty1) - fmaxf(py0, ty0), 0.0f);
        float inter = iw * ih;
        float uni   = pa + ta - inter;

        float cw = fmaxf(px1, tx1) - fminf(px0, tx0);  // >= 0 always
        float ch = fmaxf(py1, ty1) - fminf(py0, ty0);  // >= 0 always
        float ca = cw * ch;

        // cost = 5*cbbox + (2*ccls + 2) - 2*inter/uni - 2*uni/ca
        float c = fmaf(5.0f, cbbox, clsr[ql]);
        c = fmaf(-2.0f * inter, fast_rcp(uni), c);
        c = fmaf(-2.0f * uni,   fast_rcp(ca),  c);

        if (c != c) c = 1.0f;   // nan_to_num; |finite c| << 1e6, clamp no-op

        op[(size_t)ql * T] = c; // lane-contiguous 4B store, coalesced
    }
}

extern "C" void kernel_launch(void* const* d_in, const int* in_sizes, int n_in,
                              void* d_out, int out_size, void* d_ws, size_t ws_size,
                              hipStream_t stream) {
    const float* logits  = (const float*)d_in[0];  // [B,Q,C]
    const float* pboxes  = (const float*)d_in[1];  // [B,Q,4]
    const int*   tlabels = (const int*)  d_in[2];  // [B,T]
    const float* tboxes  = (const float*)d_in[3];  // [B,T,4]
    float* out = (float*)d_out;                    // [B,Q,T]

    dim3 grid(B * (Q / QTILE));   // 2880 blocks
    dim3 block(BLOCK);
    matcher_cost_kernel<<<grid, block, 0, stream>>>(logits, pboxes, tlabels, tboxes, out);
}